// Round 1
// baseline (734.231 us; speedup 1.0000x reference)
//
#include <hip/hip_runtime.h>

#define IMG 224
#define PP  16
#define SS  8
#define EE  128
#define NN  27      // patches per dim
#define LL  729
#define KK  256     // patch pixels
#define BB  64
#define IMG2 (IMG*IMG)

// MT[c][j][k] = sum_e W_dec[c][k][e] * W_enc[c][e][j]   (transposed combined matrix)
__global__ void precompute_MT(const float* __restrict__ W_enc,
                              const float* __restrict__ W_dec,
                              float* __restrict__ MT) {
    int j = blockIdx.x;   // 0..255
    int c = blockIdx.y;   // 0..2
    int k = threadIdx.x;  // 0..255
    const float* wd = W_dec + (size_t)(c*KK + k)*EE;
    const float* we = W_enc + (size_t)c*EE*KK + j;
    float acc = 0.f;
    #pragma unroll 8
    for (int e = 0; e < EE; ++e)
        acc = fmaf(wd[e], we[(size_t)e*KK], acc);
    MT[((size_t)c*KK + j)*KK + k] = acc;
}

// v[c][k] = b_dec[c][k] + sum_e W_dec[c][k][e] * b_enc[c][e]
__global__ void precompute_v(const float* __restrict__ b_enc,
                             const float* __restrict__ W_dec,
                             const float* __restrict__ b_dec,
                             float* __restrict__ v) {
    int c = blockIdx.x;
    int k = threadIdx.x;
    const float* wd = W_dec + (size_t)(c*KK + k)*EE;
    const float* be = b_enc + c*EE;
    float acc = b_dec[c*KK + k];
    #pragma unroll 8
    for (int e = 0; e < EE; ++e)
        acc = fmaf(wd[e], be[e], acc);
    v[c*KK + k] = acc;
}

__device__ __forceinline__ float inv_cnt(int y) {
    int hi = min(y >> 3, NN - 1);
    int lo = (y >= SS) ? ((y - SS) >> 3) : 0;
    return 1.0f / (float)(hi - lo + 1);   // count in {1,2} -> exact pow2 inverse
}

__global__ __launch_bounds__(256)
void patch_ae_main(const float* __restrict__ x,
                   const float* __restrict__ MT,
                   const float* __restrict__ v,
                   float* __restrict__ out) {
    int ny = blockIdx.x;   // 0..26 patch row
    int c  = blockIdx.y;   // 0..2
    int b  = blockIdx.z;   // 0..63
    int t  = threadIdx.x;

    __shared__ float xs[PP*IMG + 64];   // 16 x 224 strip + pad (pg=3,i=6 dummy reads)

    // stage input strip: rows [8*ny, 8*ny+16), all 224 cols
    const float* xin = x + (size_t)(b*3 + c)*IMG2 + (size_t)(ny*SS)*IMG;
    for (int i = t; i < PP*IMG; i += 256)
        xs[i] = xin[i];
    // zero the pad so dummy lanes never make NaNs
    if (t < 64) xs[PP*IMG + t] = 0.f;
    __syncthreads();

    int kband = t & 63;     // 0..63  -> k0 = 4*kband
    int pg    = t >> 6;     // 0..3   -> patches p = pg + 4*i
    int k0    = kband * 4;

    float acc[7][4];
    #pragma unroll
    for (int i = 0; i < 7; ++i)
        #pragma unroll
        for (int kk = 0; kk < 4; ++kk) acc[i][kk] = 0.f;

    float vk[4];
    #pragma unroll
    for (int kk = 0; kk < 4; ++kk) vk[kk] = v[c*KK + k0 + kk];

    const float4* MT4 = (const float4*)(MT + (size_t)c*KK*KK);

    #pragma unroll 4
    for (int j = 0; j < KK; ++j) {
        float4 m = MT4[j*64 + kband];          // M^T[j][k0..k0+3], coalesced
        int base = (j >> 4)*IMG + (j & 15) + pg*SS;
        #pragma unroll
        for (int i = 0; i < 7; ++i) {
            float pv = xs[base + i*32];        // patch p = pg+4i, wave-uniform broadcast
            acc[i][0] = fmaf(m.x, pv, acc[i][0]);
            acc[i][1] = fmaf(m.y, pv, acc[i][1]);
            acc[i][2] = fmaf(m.z, pv, acc[i][2]);
            acc[i][3] = fmaf(m.w, pv, acc[i][3]);
        }
    }

    float* outp = out + (size_t)(b*3 + c)*IMG2;
    #pragma unroll
    for (int kk = 0; kk < 4; ++kk) {
        int k  = k0 + kk;
        int ky = k >> 4, kx = k & 15;
        int y  = ny*SS + ky;
        float ivy = inv_cnt(y);
        #pragma unroll
        for (int i = 0; i < 7; ++i) {
            int p = pg + 4*i;
            if (p < NN) {
                int xc = p*SS + kx;
                float w = (acc[i][kk] + vk[kk]) * ivy * inv_cnt(xc);
                atomicAdd(&outp[y*IMG + xc], w);
            }
        }
    }
}

extern "C" void kernel_launch(void* const* d_in, const int* in_sizes, int n_in,
                              void* d_out, int out_size, void* d_ws, size_t ws_size,
                              hipStream_t stream) {
    const float* x     = (const float*)d_in[0];
    const float* W_enc = (const float*)d_in[1];
    const float* b_enc = (const float*)d_in[2];
    const float* W_dec = (const float*)d_in[3];
    const float* b_dec = (const float*)d_in[4];
    float* out = (float*)d_out;

    float* MT = (float*)d_ws;           // 3*256*256 floats = 786 KB
    float* v  = MT + 3*KK*KK;           // 768 floats

    hipMemsetAsync(d_out, 0, (size_t)out_size*sizeof(float), stream);
    precompute_MT<<<dim3(KK, 3), KK, 0, stream>>>(W_enc, W_dec, MT);
    precompute_v<<<3, KK, 0, stream>>>(b_enc, W_dec, b_dec, v);
    patch_ae_main<<<dim3(NN, 3, BB), 256, 0, stream>>>(x, MT, v, out);
}

// Round 2
// 83.107 us; speedup vs baseline: 8.8347x; 8.8347x over previous
//
#include <hip/hip_runtime.h>

#define IMG   224
#define IMG2  (IMG*IMG)
#define NN    27          // patches per dim
#define KK    256         // pixels per patch
#define EE    128
#define NSTRIP 28         // output 8-row strips

typedef float f32x4 __attribute__((ext_vector_type(4)));
typedef short s16x8 __attribute__((ext_vector_type(8)));

__device__ __forceinline__ unsigned short f2bf(float f) {
    unsigned int u = __float_as_uint(f);
    u = (u + 0x7fffu + ((u >> 16) & 1u)) >> 16;   // RNE (inputs finite)
    return (unsigned short)u;
}

// M[c][k][j] = sum_e W_dec[c][k][e] * W_enc[c][e][j], packed in MFMA A-frag order:
// APK[c][kf(16)][jb(8)][lane(64)][i(8)] = bf16(M[kf*16 + (lane&15)][jb*32 + 8*(lane>>4) + i])
__global__ void pack_M(const float* __restrict__ W_enc, const float* __restrict__ W_dec,
                       unsigned short* __restrict__ APK) {
    int k = blockIdx.x, c = blockIdx.y, j = threadIdx.x;
    const float* wd = W_dec + ((size_t)c*KK + k)*EE;
    const float* we = W_enc + (size_t)c*EE*KK + j;
    float acc = 0.f;
    #pragma unroll 8
    for (int e = 0; e < EE; ++e) acc = fmaf(wd[e], we[(size_t)e*KK], acc);
    int kf = k >> 4, kr = k & 15, jb = j >> 5, g = (j >> 3) & 3, i = j & 7;
    APK[(size_t)c*65536 + (((kf*8 + jb)*64) + g*16 + kr)*8 + i] = f2bf(acc);
}

// v[c][k] = b_dec[c][k] + sum_e W_dec[c][k][e] * b_enc[c][e]   (fp32)
__global__ void precompute_v(const float* __restrict__ b_enc,
                             const float* __restrict__ W_dec,
                             const float* __restrict__ b_dec,
                             float* __restrict__ v) {
    int c = blockIdx.x;
    int k = threadIdx.x;
    const float* wd = W_dec + ((size_t)c*KK + k)*EE;
    const float* be = b_enc + c*EE;
    float acc = b_dec[c*KK + k];
    #pragma unroll 8
    for (int e = 0; e < EE; ++e) acc = fmaf(wd[e], be[e], acc);
    v[c*KK + k] = acc;
}

__global__ __launch_bounds__(256)
void patch_ae_mfma(const float* __restrict__ x, const unsigned short* __restrict__ APK,
                   const float* __restrict__ v, float* __restrict__ out) {
    const int s = blockIdx.x;        // output strip: rows [8s, 8s+8)
    const int c = blockIdx.y;
    const int b = blockIdx.z;
    const int tid  = threadIdx.x;
    const int lane = tid & 63, wave = tid >> 6;

    __shared__ __align__(16) unsigned short strip[24*264]; // image rows [8s-8, 8s+16), bf16, zero-padded
    __shared__ __align__(16) float rec[2][32][132];        // [prow][patch][k_local], +4 pad
    __shared__ float vsh[256];

    if (tid < 256) vsh[tid] = v[c*256 + tid];

    // ---- stage input strip (f32 -> bf16), zero-fill out-of-image and col pad ----
    {
        const float* xb = x + (size_t)(b*3 + c)*IMG2;
        const int ybase = 8*s - 8;
        for (int idx = tid; idx < 24*66; idx += 256) {
            int r  = idx / 66, c4 = idx - r*66;
            int yr = ybase + r;
            float4 xv = make_float4(0.f, 0.f, 0.f, 0.f);
            if ((unsigned)yr < IMG && c4 < 56)
                xv = ((const float4*)(xb + (size_t)yr*IMG))[c4];
            unsigned int lo = (unsigned int)f2bf(xv.x) | ((unsigned int)f2bf(xv.y) << 16);
            unsigned int hi = (unsigned int)f2bf(xv.z) | ((unsigned int)f2bf(xv.w) << 16);
            *((uint2*)&strip[r*264 + c4*4]) = make_uint2(lo, hi);
        }
    }
    __syncthreads();

    // ---- MFMA: rec[k][p] = sum_j M[k][j] * patch[p][j] ----
    {
        const int prow    = wave >> 1;        // 0: ny=s (strip row 8), 1: ny=s-1 (strip row 0)
        const int kq      = wave & 1;         // k-half within prow
        const int rowbase = prow ? 0 : 8;
        const int kfbase  = prow*8 + kq*4;    // global k-fragment base (k/16)

        f32x4 acc[4][2];
        #pragma unroll
        for (int f = 0; f < 4; ++f)
            #pragma unroll
            for (int pf = 0; pf < 2; ++pf)
                acc[f][pf] = (f32x4){0.f, 0.f, 0.f, 0.f};

        const int g = lane >> 4, lr = lane & 15;
        const s16x8* APKc = (const s16x8*)(APK + (size_t)c*65536);

        #pragma unroll
        for (int jb = 0; jb < 8; ++jb) {
            const int jy  = 2*jb + (g >> 1);
            const int jx0 = (g & 1) * 8;
            s16x8 bfrag[2];
            #pragma unroll
            for (int pf = 0; pf < 2; ++pf) {
                int col = 8*(pf*16 + lr) + jx0;             // image col of first elem
                bfrag[pf] = *((const s16x8*)&strip[(rowbase + jy)*264 + col]);
            }
            #pragma unroll
            for (int f = 0; f < 4; ++f) {
                s16x8 afrag = APKc[((kfbase + f)*8 + jb)*64 + lane];
                acc[f][0] = __builtin_amdgcn_mfma_f32_16x16x32_bf16(afrag, bfrag[0], acc[f][0], 0, 0, 0);
                acc[f][1] = __builtin_amdgcn_mfma_f32_16x16x32_bf16(afrag, bfrag[1], acc[f][1], 0, 0, 0);
            }
        }

        // D layout: col(=patch) = lane&15, row(=k) = (lane>>4)*4 + reg
        #pragma unroll
        for (int f = 0; f < 4; ++f)
            #pragma unroll
            for (int pf = 0; pf < 2; ++pf) {
                int klocal = kq*64 + f*16 + g*4;
                int p      = pf*16 + lr;
                *((f32x4*)&rec[prow][p][klocal]) = acc[f][pf];
            }
    }
    __syncthreads();

    // ---- combine overlaps + bias, write each pixel once ----
    {
        float* orow = out + (size_t)(b*3 + c)*IMG2 + (size_t)(8*s)*IMG;
        const int has0 = (s < NSTRIP-1);   // ny=s exists
        const int has1 = (s > 0);          // ny=s-1 exists
        #pragma unroll
        for (int ii = 0; ii < 7; ++ii) {
            int idx = tid + ii*256;                 // 0..1791 = 8 rows x 224 cols
            int ry  = idx / 224, xc = idx - ry*224;
            int pmin = (xc >= 8) ? ((xc - 8) >> 3) : 0;
            int pmax = min(xc >> 3, NN-1);
            float sum = 0.f;
            for (int p = pmin; p <= pmax; ++p) {
                int kl = ry*16 + (xc - 8*p);
                if (has0) sum += rec[0][p][kl] + vsh[kl];
                if (has1) sum += rec[1][p][kl] + vsh[128 + kl];
            }
            int shift = (has0 & has1) + (pmax - pmin);          // log2(count), count in {1,2,4}
            float inv = __int_as_float(0x3f800000 - (shift << 23)); // exact 1/2^shift
            orow[idx] = sum * inv;
        }
    }
}

extern "C" void kernel_launch(void* const* d_in, const int* in_sizes, int n_in,
                              void* d_out, int out_size, void* d_ws, size_t ws_size,
                              hipStream_t stream) {
    (void)in_sizes; (void)n_in; (void)out_size; (void)ws_size;
    const float* x     = (const float*)d_in[0];
    const float* W_enc = (const float*)d_in[1];
    const float* b_enc = (const float*)d_in[2];
    const float* W_dec = (const float*)d_in[3];
    const float* b_dec = (const float*)d_in[4];
    float* out = (float*)d_out;

    float*          v   = (float*)d_ws;                         // 768 f32
    unsigned short* APK = (unsigned short*)((char*)d_ws + 4096); // 3 x 65536 bf16 = 384 KB

    precompute_v<<<3, 256, 0, stream>>>(b_enc, W_dec, b_dec, v);
    pack_M<<<dim3(KK, 3), 256, 0, stream>>>(W_enc, W_dec, APK);
    patch_ae_mfma<<<dim3(NSTRIP, 3, 64), 256, 0, stream>>>(x, APK, v, out);
}

// Round 3
// 52.661 us; speedup vs baseline: 13.9427x; 1.5782x over previous
//
#include <hip/hip_runtime.h>

#define IMG   224
#define IMG2  (IMG*IMG)
#define NN    27          // patches per dim
#define KK    256         // pixels per patch
#define EE    128
#define NSTRIP 28         // output 8-row strips

typedef float f32x4 __attribute__((ext_vector_type(4)));
typedef short s16x8 __attribute__((ext_vector_type(8)));

__device__ __forceinline__ unsigned short f2bf(float f) {
    unsigned int u = __float_as_uint(f);
    u = (u + 0x7fffu + ((u >> 16) & 1u)) >> 16;   // RNE (inputs finite)
    return (unsigned short)u;
}
__device__ __forceinline__ float bf2f(unsigned short u) {
    return __uint_as_float((unsigned int)u << 16);
}

// M[c][k][j] = sum_e W_dec[c][k][e]*W_enc[c][e][j], packed in MFMA A-frag order:
// APK[c][kf(16)][jb(8)][lane(64)][i(8)] = bf16(M[kf*16+(lane&15)][jb*32+8*(lane>>4)+i])
// Also computes v[c][k] = b_dec[c][k] + sum_e W_dec[c][k][e]*b_enc[c][e].
__global__ void pack_M(const float* __restrict__ W_enc, const float* __restrict__ W_dec,
                       const float* __restrict__ b_enc, const float* __restrict__ b_dec,
                       unsigned short* __restrict__ APK, float* __restrict__ v) {
    int k = blockIdx.x, c = blockIdx.y, j = threadIdx.x;
    const float* wd = W_dec + ((size_t)c*KK + k)*EE;
    const float* we = W_enc + (size_t)c*EE*KK + j;
    float acc = 0.f;
    #pragma unroll 8
    for (int e = 0; e < EE; ++e) acc = fmaf(wd[e], we[(size_t)e*KK], acc);
    int kf = k >> 4, kr = k & 15, jb = j >> 5, g = (j >> 3) & 3, i = j & 7;
    APK[(size_t)c*65536 + (((kf*8 + jb)*64) + g*16 + kr)*8 + i] = f2bf(acc);

    __shared__ float pv[128];
    if (j < EE) pv[j] = wd[j] * b_enc[c*EE + j];
    __syncthreads();
    for (int off = 64; off > 0; off >>= 1) {
        if (j < off) pv[j] += pv[j + off];
        __syncthreads();
    }
    if (j == 0) v[c*KK + k] = pv[0] + b_dec[c*KK + k];
}

__global__ __launch_bounds__(256, 5)
void patch_ae_mfma(const float* __restrict__ x, const unsigned short* __restrict__ APK,
                   const float* __restrict__ v, float* __restrict__ out) {
    // bijective XCD swizzle: 5376 blocks = 8 XCDs x 672; same-XCD neighbors share strip rows
    const int hid = blockIdx.x + NSTRIP*(blockIdx.y + 3*blockIdx.z);
    const int lid = (hid & 7)*672 + (hid >> 3);
    const int s  = lid % NSTRIP;
    const int t2 = lid / NSTRIP;
    const int c  = t2 % 3;
    const int b  = t2 / 3;

    const int tid  = threadIdx.x;
    const int lane = tid & 63, wave = tid >> 6;

    __shared__ __align__(16) unsigned short strip[24*264];    // 12672 B
    __shared__ __align__(16) unsigned short rec[2][32][136];  // 17408 B, stride 136 (68 dw = 4 mod 32)
    __shared__ __align__(16) float vsh[256];                  // 1024 B

    vsh[tid] = v[c*256 + tid];

    // wave constants
    const int prow    = wave >> 1;       // 0: ny=s (strip row 8), 1: ny=s-1 (strip row 0)
    const int kq      = wave & 1;
    const int rowbase = prow ? 0 : 8;
    const int kfbase  = prow*8 + kq*4;
    const int g = lane >> 4, lr = lane & 15;
    const s16x8* APKc = (const s16x8*)(APK + (size_t)c*65536);

    // A prefetch for jb=0 — in flight during staging
    s16x8 aNext[4];
    #pragma unroll
    for (int f = 0; f < 4; ++f) aNext[f] = APKc[((kfbase + f)*8 + 0)*64 + lane];

    // ---- stage input strip rows [8s-8, 8s+16) as bf16, zero-padded ----
    {
        const float* xb = x + (size_t)(b*3 + c)*IMG2;
        const int ybase = 8*s - 8;
        #pragma unroll
        for (int it = 0; it < 7; ++it) {
            int idx = tid + it*256;
            if (idx < 24*66) {
                int r  = idx / 66, c4 = idx - r*66;
                int yr = ybase + r;
                float4 xv = make_float4(0.f, 0.f, 0.f, 0.f);
                if ((unsigned)yr < IMG && c4 < 56)
                    xv = ((const float4*)(xb + (size_t)yr*IMG))[c4];
                unsigned int lo = (unsigned int)f2bf(xv.x) | ((unsigned int)f2bf(xv.y) << 16);
                unsigned int hi = (unsigned int)f2bf(xv.z) | ((unsigned int)f2bf(xv.w) << 16);
                *((uint2*)&strip[r*264 + c4*4]) = make_uint2(lo, hi);
            }
        }
    }
    __syncthreads();

    // ---- MFMA with 1-deep A pipeline ----
    {
        f32x4 acc[4][2];
        #pragma unroll
        for (int f = 0; f < 4; ++f)
            #pragma unroll
            for (int pf = 0; pf < 2; ++pf)
                acc[f][pf] = (f32x4){0.f, 0.f, 0.f, 0.f};

        #pragma unroll
        for (int jb = 0; jb < 8; ++jb) {
            s16x8 aCur[4];
            #pragma unroll
            for (int f = 0; f < 4; ++f) aCur[f] = aNext[f];
            if (jb < 7) {
                #pragma unroll
                for (int f = 0; f < 4; ++f)
                    aNext[f] = APKc[((kfbase + f)*8 + (jb+1))*64 + lane];
            }
            const int jy  = 2*jb + (g >> 1);
            const int jx0 = (g & 1)*8;
            s16x8 bfrag[2];
            bfrag[0] = *((const s16x8*)&strip[(rowbase + jy)*264 + 8*lr        + jx0]);
            bfrag[1] = *((const s16x8*)&strip[(rowbase + jy)*264 + 8*(16 + lr) + jx0]);
            #pragma unroll
            for (int f = 0; f < 4; ++f) {
                acc[f][0] = __builtin_amdgcn_mfma_f32_16x16x32_bf16(aCur[f], bfrag[0], acc[f][0], 0, 0, 0);
                acc[f][1] = __builtin_amdgcn_mfma_f32_16x16x32_bf16(aCur[f], bfrag[1], acc[f][1], 0, 0, 0);
            }
        }

        // bias + bf16 store: rec[prow][p][klocal] holds k = prow*128 + klocal
        #pragma unroll
        for (int f = 0; f < 4; ++f) {
            int klocal = kq*64 + f*16 + g*4;
            f32x4 bias = *((const f32x4*)&vsh[prow*128 + klocal]);
            #pragma unroll
            for (int pf = 0; pf < 2; ++pf) {
                f32x4 r = acc[f][pf] + bias;
                int p = pf*16 + lr;
                unsigned int lo = (unsigned int)f2bf(r.x) | ((unsigned int)f2bf(r.y) << 16);
                unsigned int hi = (unsigned int)f2bf(r.z) | ((unsigned int)f2bf(r.w) << 16);
                *((uint2*)&rec[prow][p][klocal]) = make_uint2(lo, hi);
            }
        }
    }
    __syncthreads();

    // ---- combine overlaps, write each pixel once (thread = column, 8 rows) ----
    if (tid < 224) {
        const int xc = tid;
        const int p1 = xc >> 3;
        const int v1 = (p1 <= NN-1);
        const int p0v = (p1 > 0) ? p1 - 1 : 0;
        const int v0 = (p1 > 0);
        const int dx1 = xc & 7, dx0 = dx1 + 8;
        const int h0 = (s < NSTRIP-1);
        const int h1 = (s > 0);
        const int shift = (v0 & v1) + (h0 & h1);
        const float inv = __int_as_float(0x3f800000 - (shift << 23)); // exact 1/2^shift
        float* orow = out + (size_t)(b*3 + c)*IMG2 + (size_t)(8*s)*IMG + xc;
        #pragma unroll
        for (int ry = 0; ry < 8; ++ry) {
            int kl1 = ry*16 + dx1, kl0 = ry*16 + dx0;
            float sum = 0.f;
            if (v1) {
                if (h0) sum += bf2f(rec[0][p1][kl1]);
                if (h1) sum += bf2f(rec[1][p1][kl1]);
            }
            if (v0) {
                if (h0) sum += bf2f(rec[0][p0v][kl0]);
                if (h1) sum += bf2f(rec[1][p0v][kl0]);
            }
            orow[(size_t)ry*IMG] = sum * inv;
        }
    }
}

extern "C" void kernel_launch(void* const* d_in, const int* in_sizes, int n_in,
                              void* d_out, int out_size, void* d_ws, size_t ws_size,
                              hipStream_t stream) {
    (void)in_sizes; (void)n_in; (void)out_size; (void)ws_size;
    const float* x     = (const float*)d_in[0];
    const float* W_enc = (const float*)d_in[1];
    const float* b_enc = (const float*)d_in[2];
    const float* W_dec = (const float*)d_in[3];
    const float* b_dec = (const float*)d_in[4];
    float* out = (float*)d_out;

    float*          v   = (float*)d_ws;                          // 768 f32
    unsigned short* APK = (unsigned short*)((char*)d_ws + 4096); // 3 x 65536 bf16 = 384 KB

    pack_M<<<dim3(KK, 3), 256, 0, stream>>>(W_enc, W_dec, b_enc, b_dec, APK, v);
    patch_ae_mfma<<<dim3(NSTRIP, 3, 64), 256, 0, stream>>>(x, APK, v, out);
}